// Round 4
// baseline (198.185 us; speedup 1.0000x reference)
//
#include <hip/hip_runtime.h>

// Problem shapes (fixed by setup_inputs):
//   count_logits    : (16, 21)           fp32   -> d_in[0]
//   pred_heatmaps   : (16,20,17,64,64)   fp32   -> d_in[1]  (89.13 MB)
//   pred_conf_logits: (16, 20)           fp32   -> d_in[2]
//   gt_heatmaps     : (16,20,17,64,64)   fp32   -> d_in[3]  (89.13 MB)
//   count           : (16,)              int32  -> d_in[4]
//   mask            : (16, 20)           int32  -> d_in[5]
// Output: scalar total loss (fp32).
//
// Two-kernel structure (round-1 proven; round-2 fusion via device-scope
// atomics cost ~100 us -- do not re-fuse).
// Round 4: per-INSTRUCTION coalescing. Rounds 1/3 gave each lane a
// contiguous 32/64B chunk, so each load instruction had lanes strided by
// 32/64B (4x transaction inflation). Now each WAVE owns a 4KB super-unit:
// lane i loads base+i, base+64+i, ... -> every global_load_dwordx4 is
// 64 lanes x 16B = 1KB contiguous. 8 independent loads in flight/iter.

#define B_      16
#define P_      20
#define NBP     (B_ * P_)          // 320 slices
#define KHW     (17 * 64 * 64)     // 69632 floats per slice
#define KHW4    (KHW / 4)          // 17408 float4 per slice
#define SU_PER_SLICE (KHW4 / 256)  // 68 super-units (256 float4 = 4KB) per slice
#define NBLOCKS 2048               // 8 blocks/CU * 256 CUs, fully resident
#define NTHREADS 256
#define WAVES_PER_BLOCK (NTHREADS / 64)

#define PEAK_THRESH 0.2f
#define PEAK_WEIGHT 5.0f

__device__ __forceinline__ float wdiff4(const float4 p, const float4 g) {
    float d, w, a;
    d = p.x - g.x; w = (g.x > PEAK_THRESH) ? PEAK_WEIGHT : 1.0f; a  = d * d * w;
    d = p.y - g.y; w = (g.y > PEAK_THRESH) ? PEAK_WEIGHT : 1.0f; a += d * d * w;
    d = p.z - g.z; w = (g.z > PEAK_THRESH) ? PEAK_WEIGHT : 1.0f; a += d * d * w;
    d = p.w - g.w; w = (g.w > PEAK_THRESH) ? PEAK_WEIGHT : 1.0f; a += d * d * w;
    return a;
}

__global__ __launch_bounds__(NTHREADS)
void hm_partial_kernel(const float4* __restrict__ pred,
                       const float4* __restrict__ gt,
                       const int*    __restrict__ mask,
                       float*        __restrict__ partial) {
    // --- mask compaction: wave 0 builds the active-slice list in LDS ---
    __shared__ int s_act[NBP];
    __shared__ int s_cnt;
    const int lane = threadIdx.x & 63;
    if (threadIdx.x < 64) {                       // wave 0, all 64 lanes active
        int base = 0;
        #pragma unroll
        for (int r = 0; r < NBP / 64; ++r) {      // 5 rounds of 64
            const int idx = r * 64 + lane;
            const bool m = (mask[idx] != 0);
            const unsigned long long bal = __ballot(m);
            if (m) {
                const int pos = __popcll(bal & ((1ull << lane) - 1ull));
                s_act[base + pos] = idx;
            }
            base += __popcll(bal);
        }
        if (lane == 0) s_cnt = base;
    }
    __syncthreads();

    // --- wave-based streaming over ACTIVE super-units (4KB/tensor each) ---
    const int wid    = blockIdx.x * WAVES_PER_BLOCK + (threadIdx.x >> 6);
    const int nwaves = gridDim.x * WAVES_PER_BLOCK;        // 8192
    const int total_su = s_cnt * SU_PER_SLICE;             // <= 21760
    float acc = 0.0f;
    for (int su = wid; su < total_su; su += nwaves) {
        const int slice = su / SU_PER_SLICE;               // wave-uniform
        const int off   = su - slice * SU_PER_SLICE;       // 0..67
        const int base  = s_act[slice] * KHW4 + off * 256; // float4 index
        // 8 independent, per-instruction-coalesced 1KB loads
        const float4 p0 = pred[base + lane];
        const float4 p1 = pred[base + 64  + lane];
        const float4 p2 = pred[base + 128 + lane];
        const float4 p3 = pred[base + 192 + lane];
        const float4 g0 = gt[base + lane];
        const float4 g1 = gt[base + 64  + lane];
        const float4 g2 = gt[base + 128 + lane];
        const float4 g3 = gt[base + 192 + lane];
        acc += wdiff4(p0, g0);
        acc += wdiff4(p1, g1);
        acc += wdiff4(p2, g2);
        acc += wdiff4(p3, g3);
    }

    // --- wave reduce (width 64) then block reduce ---
    #pragma unroll
    for (int off = 32; off > 0; off >>= 1) acc += __shfl_down(acc, off);

    __shared__ float s[WAVES_PER_BLOCK];
    if ((threadIdx.x & 63) == 0) s[threadIdx.x >> 6] = acc;
    __syncthreads();
    if (threadIdx.x == 0) {
        float t = 0.0f;
        #pragma unroll
        for (int w = 0; w < WAVES_PER_BLOCK; ++w) t += s[w];
        partial[blockIdx.x] = t;
    }
}

__global__ __launch_bounds__(64)
void finalize_kernel(const float* __restrict__ partial,
                     const float* __restrict__ count_logits,
                     const int*   __restrict__ count,
                     const float* __restrict__ conf_logits,
                     const int*   __restrict__ mask,
                     float*       __restrict__ out) {
    const int lane = threadIdx.x;  // 64 threads, one wave

    // 1) heatmap diff sum over block partials
    float ds = 0.0f;
    for (int i = lane; i < NBLOCKS; i += 64) ds += partial[i];

    // 2) mask sum + focal loss over the 320 conf logits
    float ms = 0.0f, fs = 0.0f;
    for (int i = lane; i < NBP; i += 64) {
        const float t = (float)mask[i];
        ms += t;
        const float l   = conf_logits[i];
        const float bce = fmaxf(l, 0.0f) - l * t + log1pf(expf(-fabsf(l)));
        const float pt  = expf(-bce);
        const float om  = 1.0f - pt;
        fs += om * om * bce;     // gamma = 2
    }

    // 3) count cross-entropy: lane b < 16 handles row b (21 logits)
    float ce = 0.0f;
    if (lane < B_) {
        const float* row = count_logits + lane * (P_ + 1);
        float mx = row[0];
        #pragma unroll
        for (int j = 1; j < P_ + 1; ++j) mx = fmaxf(mx, row[j]);
        float se = 0.0f;
        #pragma unroll
        for (int j = 0; j < P_ + 1; ++j) se += expf(row[j] - mx);
        const float lse = mx + logf(se);
        ce = -(row[count[lane]] - lse);
    }

    // wave reduce all four
    #pragma unroll
    for (int off = 32; off > 0; off >>= 1) {
        ds += __shfl_down(ds, off);
        ms += __shfl_down(ms, off);
        fs += __shfl_down(fs, off);
        ce += __shfl_down(ce, off);
    }

    if (lane == 0) {
        const float loss_count = ce / (float)B_;
        const float loss_conf  = fs / (float)NBP;
        const float hm         = ds / (ms * (float)KHW + 1e-6f);
        const float loss_hm    = (ms > 0.0f) ? hm : 0.0f;
        out[0] = 1.0f * loss_count + 10.0f * loss_hm + 1.5f * loss_conf;
    }
}

extern "C" void kernel_launch(void* const* d_in, const int* in_sizes, int n_in,
                              void* d_out, int out_size, void* d_ws, size_t ws_size,
                              hipStream_t stream) {
    const float* count_logits = (const float*)d_in[0];
    const float* pred_hm      = (const float*)d_in[1];
    const float* conf_logits  = (const float*)d_in[2];
    const float* gt_hm        = (const float*)d_in[3];
    const int*   count        = (const int*)d_in[4];
    const int*   mask         = (const int*)d_in[5];
    float*       out          = (float*)d_out;
    float*       partial      = (float*)d_ws;   // NBLOCKS floats

    hm_partial_kernel<<<NBLOCKS, NTHREADS, 0, stream>>>(
        (const float4*)pred_hm, (const float4*)gt_hm, mask, partial);

    finalize_kernel<<<1, 64, 0, stream>>>(
        partial, count_logits, count, conf_logits, mask, out);
}